// Round 7
// baseline (241.315 us; speedup 1.0000x reference)
//
#include <hip/hip_runtime.h>
#include <math.h>

typedef __bf16 b16x8 __attribute__((ext_vector_type(8)));
typedef float  f32x4 __attribute__((ext_vector_type(4)));
typedef float  f32x2a __attribute__((ext_vector_type(2), aligned(4)));  // 4-byte-aligned float2

#define B_    8
#define CIN_  64
#define COUT_ 64
#define Hs    96
#define Ws    96
#define PLANE (Hs*Ws)        // 9216
#define IMG   (CIN_*PLANE)   // 589824
#define NP    (B_*PLANE)     // 73728
#define NBLK  (NP/64)        // 1152

__device__ __forceinline__ int swz(int bid) { return (bid & 7) * (NBLK / 8) + (bid >> 3); }

// Pre-swizzle weights into per-lane MFMA A-fragment order (bf16). Same as R5/R6.
__global__ void prep(const float* __restrict__ weight, const float* __restrict__ w_off,
                     __bf16* __restrict__ wAB, __bf16* __restrict__ wAO) {
    int i = blockIdx.x * 256 + threadIdx.x;
    if (i < 36864) {
        int e = i & 7, lane = (i >> 3) & 63, mt = (i >> 9) & 3, ks = (i >> 11) & 1, k = i >> 12;
        int o = mt * 16 + (lane & 15);
        int c = ks * 32 + ((lane >> 4) << 3) + e;
        wAB[i] = (__bf16)weight[o * 576 + c * 9 + k];
    }
    if (i < 18432) {
        int e = i & 7, lane = (i >> 3) & 63, mt = (i >> 9) & 1, ks = (i >> 10) & 1, t = i >> 11;
        int ch = mt * 16 + (lane & 15);
        int c  = ks * 32 + ((lane >> 4) << 3) + e;
        wAO[i] = (ch < 27) ? (__bf16)w_off[ch * 576 + c * 9 + t] : (__bf16)(0.f);
    }
}

// Barrier-free design: each wave owns a 16-px strip (M=64 x N=16 x K=576),
// stages ALL 64 channels for its own pixels into a wave-private LDS slice,
// and MFMAs from its own slice. LDS ops are in-order per wave -> zero
// __syncthreads (so no vmcnt(0) barrier drain kills the load pipeline).
// Software pipeline: tap k's combine consumes loads issued in iter k-1.
__global__ __launch_bounds__(256, 3)
void deform_mfma(const float* __restrict__ x,
                 const __bf16* __restrict__ wAO,
                 const float* __restrict__ b_off,
                 const __bf16* __restrict__ wAB,
                 const float* __restrict__ bias,
                 float* __restrict__ out) {
    __shared__ __align__(16) __bf16 sS[4][16 * 72];   // 9216 B, wave-private slices
    __shared__ float omL[4][27 * 16];                 // 6912 B, wave-private om

    int tid  = threadIdx.x;
    int lane = tid & 63;
    int g    = __builtin_amdgcn_readfirstlane(tid >> 6);
    int n    = lane & 15;    // local px index / MFMA col
    int q    = lane >> 4;    // channel quarter (staging) / k-group (fragments)

    int pg0  = swz(blockIdx.x) * 64;
    int b    = pg0 / PLANE;
    int rblk = pg0 - b * PLANE;
    int rr   = rblk + g * 16 + n;          // 16-strip stays within one image row
    int h    = rr / Ws, w = rr - h * Ws;
    const float* xq = x + b * IMG + (q * 16) * PLANE;  // lane stages c = q*16..q*16+15

    __bf16* slice = &sS[g][0];
    float*  omW   = &omL[g][0];
    const b16x8* wAOv = (const b16x8*)wAO;
    const b16x8* wABv = (const b16x8*)wAB;

    // ---------------- Phase A: offset conv via MFMA (per-wave) ----------------
    f32x4 accA0 = {0.f, 0.f, 0.f, 0.f};
    f32x4 accA1 = {0.f, 0.f, 0.f, 0.f};

    const float* pA;
    float mkA;
    {   // tap 0 addresses + issue loads
        int yy = h - 1, xx = w - 1;
        mkA = (yy >= 0 && xx >= 0) ? 1.f : 0.f;
        pA = xq + (max(yy, 0) * Ws + max(xx, 0));
    }
    float preA[16];
#pragma unroll
    for (int i = 0; i < 16; ++i) preA[i] = pA[i * PLANE];

#pragma unroll 1
    for (int t = 0; t < 9; ++t) {
        b16x8 af0 = wAOv[((t * 2 + 0) * 2 + 0) * 64 + lane];
        b16x8 af1 = wAOv[((t * 2 + 0) * 2 + 1) * 64 + lane];
        b16x8 af2 = wAOv[((t * 2 + 1) * 2 + 0) * 64 + lane];
        b16x8 af3 = wAOv[((t * 2 + 1) * 2 + 1) * 64 + lane];

        // combine tap t (waits the 16 gathers; af* issued after them stay in flight)
        b16x8 v0, v1;
#pragma unroll
        for (int i = 0; i < 8; ++i) v0[i] = (__bf16)(preA[i] * mkA);
#pragma unroll
        for (int i = 0; i < 8; ++i) v1[i] = (__bf16)(preA[i + 8] * mkA);

        if (t < 8) {   // issue tap t+1 gathers (covered by LDS+MFMA below)
            int tt = t + 1;
            int ky = tt / 3, kx = tt - ky * 3;
            int yy = h - 1 + ky, xx = w - 1 + kx;
            mkA = (yy >= 0 && yy < Hs && xx >= 0 && xx < Ws) ? 1.f : 0.f;
            pA = xq + (min(max(yy, 0), Hs - 1) * Ws + min(max(xx, 0), Ws - 1));
#pragma unroll
            for (int i = 0; i < 16; ++i) preA[i] = pA[i * PLANE];
        }

        *(b16x8*)&slice[n * 72 + q * 16]     = v0;
        *(b16x8*)&slice[n * 72 + q * 16 + 8] = v1;
        b16x8 bf0 = *(const b16x8*)&slice[n * 72 + q * 8];        // ks=0
        b16x8 bf1 = *(const b16x8*)&slice[n * 72 + 32 + q * 8];   // ks=1
        accA0 = __builtin_amdgcn_mfma_f32_16x16x32_bf16(af0, bf0, accA0, 0, 0, 0);
        accA1 = __builtin_amdgcn_mfma_f32_16x16x32_bf16(af1, bf0, accA1, 0, 0, 0);
        accA0 = __builtin_amdgcn_mfma_f32_16x16x32_bf16(af2, bf1, accA0, 0, 0, 0);
        accA1 = __builtin_amdgcn_mfma_f32_16x16x32_bf16(af3, bf1, accA1, 0, 0, 0);
    }
    // om -> wave-private LDS (C layout: row=ch=q*4+rg, col=n)
#pragma unroll
    for (int rg = 0; rg < 4; ++rg) { int ch = q * 4 + rg;      omW[ch * 16 + n] = accA0[rg] + b_off[ch]; }
#pragma unroll
    for (int rg = 0; rg < 4; ++rg) { int ch = 16 + q * 4 + rg; if (ch < 27) omW[ch * 16 + n] = accA1[rg] + b_off[ch]; }

    // ---------------- Phase B: sampling + main conv via MFMA (per-wave) ----------------
    f32x4 acc0 = {0.f, 0.f, 0.f, 0.f};
    f32x4 acc1 = {0.f, 0.f, 0.f, 0.f};
    f32x4 acc2 = {0.f, 0.f, 0.f, 0.f};
    f32x4 acc3 = {0.f, 0.f, 0.f, 0.f};

    const float *r0c, *r1c;          // current tap row-pair bases
    float a0c, b0c, a1c, b1c;        // current tap combine coefficients

    // coefficient + address calc for tap k (bilinear + clamp folded into (a,b) pairs)
#define CALC_B(kk, R0, R1, A0, B0, A1, B1) do {                                   \
        int _k = (kk);                                                            \
        float dy = omW[(2 * _k) * 16 + n];                                        \
        float dx = omW[(2 * _k + 1) * 16 + n];                                    \
        float mo = omW[(18 + _k) * 16 + n];                                       \
        float m  = 1.f / (1.f + __expf(-mo));                                     \
        int ky = _k / 3, kx = _k - ky * 3;                                        \
        float ys = (float)(h - 1 + ky) + dy;                                      \
        float xs = (float)(w - 1 + kx) + dx;                                      \
        float y0f = floorf(ys), x0f = floorf(xs);                                 \
        float ly = ys - y0f, lx = xs - x0f;                                       \
        float hy = 1.f - ly, hx = 1.f - lx;                                       \
        int y0 = (int)y0f, x0 = (int)x0f, y1 = y0 + 1, x1 = x0 + 1;               \
        bool vy0 = (y0 >= 0) && (y0 < Hs), vy1 = (y1 >= 0) && (y1 < Hs);          \
        bool vx0 = (x0 >= 0) && (x0 < Ws), vx1 = (x1 >= 0) && (x1 < Ws);          \
        float w00 = (vy0 && vx0) ? m * hy * hx : 0.f;                             \
        float w01 = (vy0 && vx1) ? m * hy * lx : 0.f;                             \
        float w10 = (vy1 && vx0) ? m * ly * hx : 0.f;                             \
        float w11 = (vy1 && vx1) ? m * ly * lx : 0.f;                             \
        int xL = max(0, min(x0, Ws - 2));                                         \
        int x0c = min(max(x0, 0), Ws - 1), x1c = min(max(x1, 0), Ws - 1);         \
        bool e0 = (x0c == xL), e1 = (x1c == xL);                                  \
        A0 = (e0 ? w00 : 0.f) + (e1 ? w01 : 0.f);  B0 = (w00 + w01) - A0;         \
        A1 = (e0 ? w10 : 0.f) + (e1 ? w11 : 0.f);  B1 = (w10 + w11) - A1;         \
        int y0c = min(max(y0, 0), Hs - 1), y1c = min(max(y1, 0), Hs - 1);         \
        R0 = xq + y0c * Ws + xL;  R1 = xq + y1c * Ws + xL;                        \
    } while (0)

    f32x2a pre0[16], pre1[16];
    CALC_B(0, r0c, r1c, a0c, b0c, a1c, b1c);
#pragma unroll
    for (int i = 0; i < 16; ++i) pre0[i] = *(const f32x2a*)(r0c + i * PLANE);
#pragma unroll
    for (int i = 0; i < 16; ++i) pre1[i] = *(const f32x2a*)(r1c + i * PLANE);

#pragma unroll 1
    for (int k = 0; k < 9; ++k) {
        b16x8 a0 = wABv[(k * 8 + 0) * 64 + lane];
        b16x8 a1 = wABv[(k * 8 + 1) * 64 + lane];
        b16x8 a2 = wABv[(k * 8 + 2) * 64 + lane];
        b16x8 a3 = wABv[(k * 8 + 3) * 64 + lane];
        b16x8 a4 = wABv[(k * 8 + 4) * 64 + lane];
        b16x8 a5 = wABv[(k * 8 + 5) * 64 + lane];
        b16x8 a6 = wABv[(k * 8 + 6) * 64 + lane];
        b16x8 a7 = wABv[(k * 8 + 7) * 64 + lane];

        // combine tap k (waits gathers issued in iter k-1; a0..a7 stay in flight)
        b16x8 v0, v1;
#pragma unroll
        for (int i = 0; i < 16; ++i) {
            float vv = pre0[i].x * a0c + pre0[i].y * b0c + pre1[i].x * a1c + pre1[i].y * b1c;
            if (i < 8) v0[i] = (__bf16)vv; else v1[i - 8] = (__bf16)vv;
        }

        if (k < 8) {   // issue tap k+1 gathers; covered by LDS + MFMA below
            const float *r0n, *r1n; float a0n, b0n, a1n, b1n;
            CALC_B(k + 1, r0n, r1n, a0n, b0n, a1n, b1n);
#pragma unroll
            for (int i = 0; i < 16; ++i) pre0[i] = *(const f32x2a*)(r0n + i * PLANE);
#pragma unroll
            for (int i = 0; i < 16; ++i) pre1[i] = *(const f32x2a*)(r1n + i * PLANE);
            a0c = a0n; b0c = b0n; a1c = a1n; b1c = b1n;
        }

        *(b16x8*)&slice[n * 72 + q * 16]     = v0;
        *(b16x8*)&slice[n * 72 + q * 16 + 8] = v1;
        b16x8 bf0 = *(const b16x8*)&slice[n * 72 + q * 8];
        b16x8 bf1 = *(const b16x8*)&slice[n * 72 + 32 + q * 8];
        acc0 = __builtin_amdgcn_mfma_f32_16x16x32_bf16(a0, bf0, acc0, 0, 0, 0);
        acc1 = __builtin_amdgcn_mfma_f32_16x16x32_bf16(a1, bf0, acc1, 0, 0, 0);
        acc2 = __builtin_amdgcn_mfma_f32_16x16x32_bf16(a2, bf0, acc2, 0, 0, 0);
        acc3 = __builtin_amdgcn_mfma_f32_16x16x32_bf16(a3, bf0, acc3, 0, 0, 0);
        acc0 = __builtin_amdgcn_mfma_f32_16x16x32_bf16(a4, bf1, acc0, 0, 0, 0);
        acc1 = __builtin_amdgcn_mfma_f32_16x16x32_bf16(a5, bf1, acc1, 0, 0, 0);
        acc2 = __builtin_amdgcn_mfma_f32_16x16x32_bf16(a6, bf1, acc2, 0, 0, 0);
        acc3 = __builtin_amdgcn_mfma_f32_16x16x32_bf16(a7, bf1, acc3, 0, 0, 0);
    }
#undef CALC_B

    // epilogue: C layout row=(q*4+rg) within m-tile, col=n -> px rr
    int ob = b * (COUT_ * PLANE) + rblk + g * 16 + n;
#pragma unroll
    for (int rg = 0; rg < 4; ++rg) { int o =      q * 4 + rg; out[ob + o * PLANE] = acc0[rg] + bias[o]; }
#pragma unroll
    for (int rg = 0; rg < 4; ++rg) { int o = 16 + q * 4 + rg; out[ob + o * PLANE] = acc1[rg] + bias[o]; }
#pragma unroll
    for (int rg = 0; rg < 4; ++rg) { int o = 32 + q * 4 + rg; out[ob + o * PLANE] = acc2[rg] + bias[o]; }
#pragma unroll
    for (int rg = 0; rg < 4; ++rg) { int o = 48 + q * 4 + rg; out[ob + o * PLANE] = acc3[rg] + bias[o]; }
}

extern "C" void kernel_launch(void* const* d_in, const int* in_sizes, int n_in,
                              void* d_out, int out_size, void* d_ws, size_t ws_size,
                              hipStream_t stream) {
    const float* x      = (const float*)d_in[0];
    const float* w_off  = (const float*)d_in[1];
    const float* b_off  = (const float*)d_in[2];
    const float* weight = (const float*)d_in[3];
    const float* bias   = (const float*)d_in[4];
    float* out = (float*)d_out;

    char* ws = (char*)d_ws;
    __bf16* wAB = (__bf16*)ws;             // 73728 B
    __bf16* wAO = (__bf16*)(ws + 73728);   // 36864 B

    prep<<<144, 256, 0, stream>>>(weight, w_off, wAB, wAO);
    deform_mfma<<<NBLK, 256, 0, stream>>>(x, wAO, b_off, wAB, bias, out);
}

// Round 8
// 176.260 us; speedup vs baseline: 1.3691x; 1.3691x over previous
//
#include <hip/hip_runtime.h>
#include <math.h>

typedef __bf16 b16x8 __attribute__((ext_vector_type(8)));
typedef float  f32x4 __attribute__((ext_vector_type(4)));
typedef float  f32x2a __attribute__((ext_vector_type(2), aligned(4)));  // 4B-aligned float2

#define B_    8
#define CIN_  64
#define COUT_ 64
#define Hs    96
#define Ws    96
#define PLANE (Hs*Ws)        // 9216
#define IMG   (CIN_*PLANE)   // 589824
#define NP    (B_*PLANE)     // 73728
#define NBLK  (NP/64)        // 1152

__device__ __forceinline__ int swz(int bid) { return (bid & 7) * (NBLK / 8) + (bid >> 3); }

// Pre-swizzle weights into per-lane MFMA A-fragment order (bf16). Same as R5-R7.
// wAB b16x8 index: (k*8 + ks*4 + mt)*64 + lane ; o = mt*16+(lane&15), c = ks*32+(lane>>4)*8+e
// wAO b16x8 index: ((t*2+ks)*2 + mt)*64 + lane ; ch = mt*16+(lane&15), c likewise
__global__ void prep(const float* __restrict__ weight, const float* __restrict__ w_off,
                     __bf16* __restrict__ wAB, __bf16* __restrict__ wAO) {
    int i = blockIdx.x * 256 + threadIdx.x;
    if (i < 36864) {
        int e = i & 7, lane = (i >> 3) & 63, mt = (i >> 9) & 3, ks = (i >> 11) & 1, k = i >> 12;
        int o = mt * 16 + (lane & 15);
        int c = ks * 32 + ((lane >> 4) << 3) + e;
        wAB[i] = (__bf16)weight[o * 576 + c * 9 + k];
    }
    if (i < 18432) {
        int e = i & 7, lane = (i >> 3) & 63, mt = (i >> 9) & 1, ks = (i >> 10) & 1, t = i >> 11;
        int ch = mt * 16 + (lane & 15);
        int c  = ks * 32 + ((lane >> 4) << 3) + e;
        wAO[i] = (ch < 27) ? (__bf16)w_off[ch * 576 + c * 9 + t] : (__bf16)(0.f);
    }
}

// Barrier-free, LDS-staging-free: lane (n,q) gathers exactly the 8 channels of
// its own MFMA B-fragment (B[k=q*8+e][n]) -> combine output IS the B operand.
// Half-tap software pipeline, issue-ordered so in-order vmcnt retirement never
// drains the prefetch:  afE | O-loads | om-prefetch | combineE(wait E) |
// 4xMFMA(wait afE) | CALC(k+1) | afO | E(k+1)-loads | combineO(wait O) | 4xMFMA.
// LDS = per-wave om[27][16] only. Zero __syncthreads.
__global__ __launch_bounds__(256, 3)
void deform_mfma(const float* __restrict__ x,
                 const __bf16* __restrict__ wAO,
                 const float* __restrict__ b_off,
                 const __bf16* __restrict__ wAB,
                 const float* __restrict__ bias,
                 float* __restrict__ out) {
    __shared__ float omL[4][27 * 16];   // 6912 B, wave-private

    int tid  = threadIdx.x;
    int lane = tid & 63;
    int g    = __builtin_amdgcn_readfirstlane(tid >> 6);
    int n    = lane & 15;    // pixel within strip / MFMA col
    int q    = lane >> 4;    // k-group: this lane owns channels q*8..q*8+7 (+32)

    int pg0  = swz(blockIdx.x) * 64;
    int b    = pg0 / PLANE;
    int rblk = pg0 - b * PLANE;
    int rr   = rblk + g * 16 + n;
    int h    = rr / Ws, w = rr - h * Ws;
    const float* xq = x + b * IMG + (q * 8) * PLANE;   // base of this lane's channel set

    float* omW = &omL[g][0];
    const b16x8* wAOv = (const b16x8*)wAO;
    const b16x8* wABv = (const b16x8*)wAB;

    // ---------------- Phase A: offset conv via MFMA, direct-to-fragment ----------------
    f32x4 accA0 = {0.f, 0.f, 0.f, 0.f};
    f32x4 accA1 = {0.f, 0.f, 0.f, 0.f};

    auto posA = [&](int t, float* mk) -> const float* {
        int ky = t / 3, kx = t - ky * 3;
        int yy = h - 1 + ky, xx = w - 1 + kx;
        *mk = (yy >= 0 && yy < Hs && xx >= 0 && xx < Ws) ? 1.f : 0.f;
        return xq + (min(max(yy, 0), Hs - 1) * Ws + min(max(xx, 0), Ws - 1));
    };

    float mkE;
    const float* pE = posA(0, &mkE);
    float eA[8];
#pragma unroll
    for (int j = 0; j < 8; ++j) eA[j] = pE[j * PLANE];

#pragma unroll 1
    for (int t = 0; t < 9; ++t) {
        b16x8 af0 = wAOv[((t * 2 + 0) * 2 + 0) * 64 + lane];   // ks0, mt0
        b16x8 af1 = wAOv[((t * 2 + 0) * 2 + 1) * 64 + lane];   // ks0, mt1
        float mkO = mkE;
        float oA[8];
#pragma unroll
        for (int j = 0; j < 8; ++j) oA[j] = pE[(32 + j) * PLANE];  // O-half, same pos

        b16x8 bf0;
#pragma unroll
        for (int j = 0; j < 8; ++j) bf0[j] = (__bf16)(eA[j] * mkE);
        accA0 = __builtin_amdgcn_mfma_f32_16x16x32_bf16(af0, bf0, accA0, 0, 0, 0);
        accA1 = __builtin_amdgcn_mfma_f32_16x16x32_bf16(af1, bf0, accA1, 0, 0, 0);

        b16x8 af2 = wAOv[((t * 2 + 1) * 2 + 0) * 64 + lane];   // ks1, mt0
        b16x8 af3 = wAOv[((t * 2 + 1) * 2 + 1) * 64 + lane];   // ks1, mt1
        if (t < 8) {   // issue next tap's E-half; covered by combineO + MFMAs
            pE = posA(t + 1, &mkE);
#pragma unroll
            for (int j = 0; j < 8; ++j) eA[j] = pE[j * PLANE];
        }

        b16x8 bf1;
#pragma unroll
        for (int j = 0; j < 8; ++j) bf1[j] = (__bf16)(oA[j] * mkO);
        accA0 = __builtin_amdgcn_mfma_f32_16x16x32_bf16(af2, bf1, accA0, 0, 0, 0);
        accA1 = __builtin_amdgcn_mfma_f32_16x16x32_bf16(af3, bf1, accA1, 0, 0, 0);
    }
    // om -> wave-private LDS (C layout: row=q*4+rg, col=n)
#pragma unroll
    for (int rg = 0; rg < 4; ++rg) { int ch = q * 4 + rg;      omW[ch * 16 + n] = accA0[rg] + b_off[ch]; }
#pragma unroll
    for (int rg = 0; rg < 4; ++rg) { int ch = 16 + q * 4 + rg; if (ch < 27) omW[ch * 16 + n] = accA1[rg] + b_off[ch]; }

    // ---------------- Phase B: sampling + main conv, direct-to-fragment ----------------
    f32x4 acc0 = {0.f, 0.f, 0.f, 0.f};
    f32x4 acc1 = {0.f, 0.f, 0.f, 0.f};
    f32x4 acc2 = {0.f, 0.f, 0.f, 0.f};
    f32x4 acc3 = {0.f, 0.f, 0.f, 0.f};

    // bilinear coefficients + row bases from pre-read om triple (clamp folded)
#define CALC_FROM(dy, dx, mo, kk, R0, R1, A0, B0, A1, B1) do {                    \
        float m  = 1.f / (1.f + __expf(-(mo)));                                   \
        int ky = (kk) / 3, kx = (kk) - ky * 3;                                    \
        float ys = (float)(h - 1 + ky) + (dy);                                    \
        float xs = (float)(w - 1 + kx) + (dx);                                    \
        float y0f = floorf(ys), x0f = floorf(xs);                                 \
        float ly = ys - y0f, lx = xs - x0f;                                       \
        float hy = 1.f - ly, hx = 1.f - lx;                                       \
        int y0 = (int)y0f, x0 = (int)x0f, y1 = y0 + 1, x1 = x0 + 1;               \
        bool vy0 = (y0 >= 0) && (y0 < Hs), vy1 = (y1 >= 0) && (y1 < Hs);          \
        bool vx0 = (x0 >= 0) && (x0 < Ws), vx1 = (x1 >= 0) && (x1 < Ws);          \
        float w00 = (vy0 && vx0) ? m * hy * hx : 0.f;                             \
        float w01 = (vy0 && vx1) ? m * hy * lx : 0.f;                             \
        float w10 = (vy1 && vx0) ? m * ly * hx : 0.f;                             \
        float w11 = (vy1 && vx1) ? m * ly * lx : 0.f;                             \
        int xL = max(0, min(x0, Ws - 2));                                         \
        int x0c = min(max(x0, 0), Ws - 1), x1c = min(max(x1, 0), Ws - 1);         \
        bool e0 = (x0c == xL), e1 = (x1c == xL);                                  \
        A0 = (e0 ? w00 : 0.f) + (e1 ? w01 : 0.f);  B0 = (w00 + w01) - A0;         \
        A1 = (e0 ? w10 : 0.f) + (e1 ? w11 : 0.f);  B1 = (w10 + w11) - A1;         \
        int y0c = min(max(y0, 0), Hs - 1), y1c = min(max(y1, 0), Hs - 1);         \
        R0 = xq + y0c * Ws + xL;  R1 = xq + y1c * Ws + xL;                        \
    } while (0)

    float a0c, b0c, a1c, b1c;
    const float *r0c, *r1c;
    {
        float dy0 = omW[0 * 16 + n], dx0 = omW[1 * 16 + n], mo0 = omW[18 * 16 + n];
        CALC_FROM(dy0, dx0, mo0, 0, r0c, r1c, a0c, b0c, a1c, b1c);
    }
    f32x2a e0v[8], e1v[8];
#pragma unroll
    for (int j = 0; j < 8; ++j) e0v[j] = *(const f32x2a*)(r0c + j * PLANE);
#pragma unroll
    for (int j = 0; j < 8; ++j) e1v[j] = *(const f32x2a*)(r1c + j * PLANE);

#pragma unroll 1
    for (int k = 0; k < 9; ++k) {
        b16x8 a0 = wABv[(k * 8 + 0) * 64 + lane];   // ks0, mt0..3
        b16x8 a1 = wABv[(k * 8 + 1) * 64 + lane];
        b16x8 a2 = wABv[(k * 8 + 2) * 64 + lane];
        b16x8 a3 = wABv[(k * 8 + 3) * 64 + lane];
        // O-half loads (same tap, channels +32)
        f32x2a o0v[8], o1v[8];
#pragma unroll
        for (int j = 0; j < 8; ++j) o0v[j] = *(const f32x2a*)(r0c + (32 + j) * PLANE);
#pragma unroll
        for (int j = 0; j < 8; ++j) o1v[j] = *(const f32x2a*)(r1c + (32 + j) * PLANE);

        // prefetch next tap's om triple (ds_read latency hidden behind combine+MFMA)
        int kn = (k < 8) ? (k + 1) : 8;
        float dyN = omW[(2 * kn) * 16 + n];
        float dxN = omW[(2 * kn + 1) * 16 + n];
        float moN = omW[(18 + kn) * 16 + n];

        float A0 = a0c, B0 = b0c, A1 = a1c, B1 = b1c;   // save for O combine

        b16x8 fe;
#pragma unroll
        for (int j = 0; j < 8; ++j)
            fe[j] = (__bf16)(e0v[j].x * a0c + e0v[j].y * b0c + e1v[j].x * a1c + e1v[j].y * b1c);
        acc0 = __builtin_amdgcn_mfma_f32_16x16x32_bf16(a0, fe, acc0, 0, 0, 0);
        acc1 = __builtin_amdgcn_mfma_f32_16x16x32_bf16(a1, fe, acc1, 0, 0, 0);
        acc2 = __builtin_amdgcn_mfma_f32_16x16x32_bf16(a2, fe, acc2, 0, 0, 0);
        acc3 = __builtin_amdgcn_mfma_f32_16x16x32_bf16(a3, fe, acc3, 0, 0, 0);

        b16x8 a4 = wABv[(k * 8 + 4) * 64 + lane];   // ks1, mt0..3
        b16x8 a5 = wABv[(k * 8 + 5) * 64 + lane];
        b16x8 a6 = wABv[(k * 8 + 6) * 64 + lane];
        b16x8 a7 = wABv[(k * 8 + 7) * 64 + lane];

        if (k < 8) {   // CALC(k+1) + issue E(k+1); covered by combineO + MFMAs below
            CALC_FROM(dyN, dxN, moN, k + 1, r0c, r1c, a0c, b0c, a1c, b1c);
#pragma unroll
            for (int j = 0; j < 8; ++j) e0v[j] = *(const f32x2a*)(r0c + j * PLANE);
#pragma unroll
            for (int j = 0; j < 8; ++j) e1v[j] = *(const f32x2a*)(r1c + j * PLANE);
        }

        b16x8 fo;
#pragma unroll
        for (int j = 0; j < 8; ++j)
            fo[j] = (__bf16)(o0v[j].x * A0 + o0v[j].y * B0 + o1v[j].x * A1 + o1v[j].y * B1);
        acc0 = __builtin_amdgcn_mfma_f32_16x16x32_bf16(a4, fo, acc0, 0, 0, 0);
        acc1 = __builtin_amdgcn_mfma_f32_16x16x32_bf16(a5, fo, acc1, 0, 0, 0);
        acc2 = __builtin_amdgcn_mfma_f32_16x16x32_bf16(a6, fo, acc2, 0, 0, 0);
        acc3 = __builtin_amdgcn_mfma_f32_16x16x32_bf16(a7, fo, acc3, 0, 0, 0);
    }
#undef CALC_FROM

    // epilogue: C layout row=(q*4+rg) within m-tile, col=n -> pixel rr
    int ob = b * (COUT_ * PLANE) + rblk + g * 16 + n;
    f32x4 bs0 = *(const f32x4*)&bias[q * 4];
    f32x4 bs1 = *(const f32x4*)&bias[16 + q * 4];
    f32x4 bs2 = *(const f32x4*)&bias[32 + q * 4];
    f32x4 bs3 = *(const f32x4*)&bias[48 + q * 4];
#pragma unroll
    for (int rg = 0; rg < 4; ++rg) { int o =      q * 4 + rg; out[ob + o * PLANE] = acc0[rg] + bs0[rg]; }
#pragma unroll
    for (int rg = 0; rg < 4; ++rg) { int o = 16 + q * 4 + rg; out[ob + o * PLANE] = acc1[rg] + bs1[rg]; }
#pragma unroll
    for (int rg = 0; rg < 4; ++rg) { int o = 32 + q * 4 + rg; out[ob + o * PLANE] = acc2[rg] + bs2[rg]; }
#pragma unroll
    for (int rg = 0; rg < 4; ++rg) { int o = 48 + q * 4 + rg; out[ob + o * PLANE] = acc3[rg] + bs3[rg]; }
}

extern "C" void kernel_launch(void* const* d_in, const int* in_sizes, int n_in,
                              void* d_out, int out_size, void* d_ws, size_t ws_size,
                              hipStream_t stream) {
    const float* x      = (const float*)d_in[0];
    const float* w_off  = (const float*)d_in[1];
    const float* b_off  = (const float*)d_in[2];
    const float* weight = (const float*)d_in[3];
    const float* bias   = (const float*)d_in[4];
    float* out = (float*)d_out;

    char* ws = (char*)d_ws;
    __bf16* wAB = (__bf16*)ws;             // 73728 B
    __bf16* wAO = (__bf16*)(ws + 73728);   // 36864 B

    prep<<<144, 256, 0, stream>>>(weight, w_off, wAB, wAO);
    deform_mfma<<<NBLK, 256, 0, stream>>>(x, wAO, b_off, wAB, bias, out);
}

// Round 9
// 148.855 us; speedup vs baseline: 1.6211x; 1.1841x over previous
//
#include <hip/hip_runtime.h>
#include <math.h>

typedef __bf16 b16x8 __attribute__((ext_vector_type(8)));
typedef float  f32x4 __attribute__((ext_vector_type(4)));

#define B_    8
#define CIN_  64
#define COUT_ 64
#define Hs    96
#define Ws    96
#define PLANE (Hs*Ws)        // 9216
#define IMG   (CIN_*PLANE)   // 589824
#define NP    (B_*PLANE)     // 73728
#define NBLK  (NP/64)        // 1152

__device__ __forceinline__ int swz(int bid) { return (bid & 7) * (NBLK / 8) + (bid >> 3); }

// Weights -> per-lane MFMA A-fragment order (bf16). Same as R5-R8.
__global__ void prep(const float* __restrict__ weight, const float* __restrict__ w_off,
                     __bf16* __restrict__ wAB, __bf16* __restrict__ wAO) {
    int i = blockIdx.x * 256 + threadIdx.x;
    if (i < 36864) {
        int e = i & 7, lane = (i >> 3) & 63, mt = (i >> 9) & 3, ks = (i >> 11) & 1, k = i >> 12;
        int o = mt * 16 + (lane & 15);
        int c = ks * 32 + ((lane >> 4) << 3) + e;
        wAB[i] = (__bf16)weight[o * 576 + c * 9 + k];
    }
    if (i < 18432) {
        int e = i & 7, lane = (i >> 3) & 63, mt = (i >> 9) & 1, ks = (i >> 10) & 1, t = i >> 11;
        int ch = mt * 16 + (lane & 15);
        int c  = ks * 32 + ((lane >> 4) << 3) + e;
        wAO[i] = (ch < 27) ? (__bf16)w_off[ch * 576 + c * 9 + t] : (__bf16)(0.f);
    }
}

// x [b][c][y][x] fp32 -> xT [b][y][x][c] bf16 (channel-last).
// One thread per pixel: reads coalesced per channel, writes 8x b128.
__global__ void xpose(const float* __restrict__ x, __bf16* __restrict__ xT) {
    int p = blockIdx.x * 256 + threadIdx.x;   // 288 blocks cover NP
    int b = p / PLANE, r = p - b * PLANE;
    const float* src = x + b * IMG + r;
    __bf16 buf[64];
#pragma unroll
    for (int c = 0; c < 64; ++c) buf[c] = (__bf16)src[c * PLANE];
    b16x8* dst = (b16x8*)(xT + (size_t)p * 64);
#pragma unroll
    for (int j = 0; j < 8; ++j) dst[j] = ((const b16x8*)buf)[j];
}

// Barrier-free, channel-last: one b128 load = one 8-channel fragment octet.
// Per tap phase B: 4 positions x 2 octets = 8 b128 loads (was 32 scattered).
// Phase A: 2 loads + cndmask per tap. Half-tap software pipeline as in R8.
__global__ __launch_bounds__(256, 3)
void deform_mfma(const __bf16* __restrict__ xT,
                 const __bf16* __restrict__ wAO,
                 const float* __restrict__ b_off,
                 const __bf16* __restrict__ wAB,
                 const float* __restrict__ bias,
                 float* __restrict__ out) {
    __shared__ float omL[4][27 * 16];   // 6912 B, wave-private

    int tid  = threadIdx.x;
    int lane = tid & 63;
    int g    = __builtin_amdgcn_readfirstlane(tid >> 6);
    int n    = lane & 15;    // pixel within strip / MFMA col
    int q    = lane >> 4;    // octet: this lane owns channels q*8..q*8+7 (ks0) / +32 (ks1)

    int pg0  = swz(blockIdx.x) * 64;
    int b    = pg0 / PLANE;
    int rblk = pg0 - b * PLANE;
    int rr   = rblk + g * 16 + n;
    int h    = rr / Ws, w = rr - h * Ws;
    const __bf16* xTb = xT + (size_t)b * PLANE * 64 + q * 8;   // +octet offset

    float* omW = &omL[g][0];
    const b16x8* wAOv = (const b16x8*)wAO;
    const b16x8* wABv = (const b16x8*)wAB;

    // ---------------- Phase A: offset conv via MFMA ----------------
    f32x4 accA0 = {0.f, 0.f, 0.f, 0.f};
    f32x4 accA1 = {0.f, 0.f, 0.f, 0.f};

    auto posA = [&](int t, bool* mk) -> const b16x8* {
        int ky = t / 3, kx = t - ky * 3;
        int yy = h - 1 + ky, xx = w - 1 + kx;
        *mk = (yy >= 0 && yy < Hs && xx >= 0 && xx < Ws);
        return (const b16x8*)(xTb + (min(max(yy, 0), Hs - 1) * Ws + min(max(xx, 0), Ws - 1)) * 64);
    };

    bool mkC;
    const b16x8* pC = posA(0, &mkC);
    b16x8 eC = pC[0], oC = pC[4];   // octet q (ks0) and octet q+32ch (ks1)
    const b16x8 ZER = {};

#pragma unroll 1
    for (int t = 0; t < 9; ++t) {
        b16x8 af0 = wAOv[((t * 2 + 0) * 2 + 0) * 64 + lane];
        b16x8 af1 = wAOv[((t * 2 + 0) * 2 + 1) * 64 + lane];
        b16x8 af2 = wAOv[((t * 2 + 1) * 2 + 0) * 64 + lane];
        b16x8 af3 = wAOv[((t * 2 + 1) * 2 + 1) * 64 + lane];

        b16x8 bf0 = mkC ? eC : ZER;
        b16x8 bf1 = mkC ? oC : ZER;

        if (t < 8) {   // prefetch next tap (covered by 4 MFMAs below)
            pC = posA(t + 1, &mkC);
            eC = pC[0]; oC = pC[4];
        }

        accA0 = __builtin_amdgcn_mfma_f32_16x16x32_bf16(af0, bf0, accA0, 0, 0, 0);
        accA1 = __builtin_amdgcn_mfma_f32_16x16x32_bf16(af1, bf0, accA1, 0, 0, 0);
        accA0 = __builtin_amdgcn_mfma_f32_16x16x32_bf16(af2, bf1, accA0, 0, 0, 0);
        accA1 = __builtin_amdgcn_mfma_f32_16x16x32_bf16(af3, bf1, accA1, 0, 0, 0);
    }
#pragma unroll
    for (int rg = 0; rg < 4; ++rg) { int ch = q * 4 + rg;      omW[ch * 16 + n] = accA0[rg] + b_off[ch]; }
#pragma unroll
    for (int rg = 0; rg < 4; ++rg) { int ch = 16 + q * 4 + rg; if (ch < 27) omW[ch * 16 + n] = accA1[rg] + b_off[ch]; }

    // ---------------- Phase B: sampling + main conv ----------------
    f32x4 acc0 = {0.f, 0.f, 0.f, 0.f};
    f32x4 acc1 = {0.f, 0.f, 0.f, 0.f};
    f32x4 acc2 = {0.f, 0.f, 0.f, 0.f};
    f32x4 acc3 = {0.f, 0.f, 0.f, 0.f};

    const b16x8 *P00, *P01, *P10, *P11;   // current tap position pointers (octet base)
    float W00, W01, W10, W11;             // current tap bilinear weights (mask folded)

#define CALC_FROM(dy, dx, mo, kk) do {                                            \
        float m  = 1.f / (1.f + __expf(-(mo)));                                   \
        int ky = (kk) / 3, kx = (kk) - ky * 3;                                    \
        float ys = (float)(h - 1 + ky) + (dy);                                    \
        float xs = (float)(w - 1 + kx) + (dx);                                    \
        float y0f = floorf(ys), x0f = floorf(xs);                                 \
        float ly = ys - y0f, lx = xs - x0f;                                       \
        float hy = 1.f - ly, hx = 1.f - lx;                                       \
        int y0 = (int)y0f, x0 = (int)x0f, y1 = y0 + 1, x1 = x0 + 1;               \
        bool vy0 = (y0 >= 0) && (y0 < Hs), vy1 = (y1 >= 0) && (y1 < Hs);          \
        bool vx0 = (x0 >= 0) && (x0 < Ws), vx1 = (x1 >= 0) && (x1 < Ws);          \
        W00 = (vy0 && vx0) ? m * hy * hx : 0.f;                                   \
        W01 = (vy0 && vx1) ? m * hy * lx : 0.f;                                   \
        W10 = (vy1 && vx0) ? m * ly * hx : 0.f;                                   \
        W11 = (vy1 && vx1) ? m * ly * lx : 0.f;                                   \
        int y0c = min(max(y0, 0), Hs - 1), y1c = min(max(y1, 0), Hs - 1);         \
        int x0c = min(max(x0, 0), Ws - 1), x1c = min(max(x1, 0), Ws - 1);         \
        P00 = (const b16x8*)(xTb + (y0c * Ws + x0c) * 64);                        \
        P01 = (const b16x8*)(xTb + (y0c * Ws + x1c) * 64);                        \
        P10 = (const b16x8*)(xTb + (y1c * Ws + x0c) * 64);                        \
        P11 = (const b16x8*)(xTb + (y1c * Ws + x1c) * 64);                        \
    } while (0)

    {
        float dy0 = omW[0 * 16 + n], dx0 = omW[1 * 16 + n], mo0 = omW[18 * 16 + n];
        CALC_FROM(dy0, dx0, mo0, 0);
    }
    b16x8 e00 = P00[0], e01 = P01[0], e10 = P10[0], e11 = P11[0];   // ks0 octets

#pragma unroll 1
    for (int k = 0; k < 9; ++k) {
        b16x8 a0 = wABv[(k * 8 + 0) * 64 + lane];
        b16x8 a1 = wABv[(k * 8 + 1) * 64 + lane];
        b16x8 a2 = wABv[(k * 8 + 2) * 64 + lane];
        b16x8 a3 = wABv[(k * 8 + 3) * 64 + lane];
        // ks1 octets (channels +32) for this tap
        b16x8 o00 = P00[4], o01 = P01[4], o10 = P10[4], o11 = P11[4];

        // prefetch next tap's om triple (LDS; latency hidden behind combine+MFMA)
        int kn = (k < 8) ? (k + 1) : 8;
        float dyN = omW[(2 * kn) * 16 + n];
        float dxN = omW[(2 * kn + 1) * 16 + n];
        float moN = omW[(18 + kn) * 16 + n];

        float V00 = W00, V01 = W01, V10 = W10, V11 = W11;   // save for ks1 combine

        b16x8 fe;
#pragma unroll
        for (int j = 0; j < 8; ++j)
            fe[j] = (__bf16)((float)e00[j] * W00 + (float)e01[j] * W01 +
                             (float)e10[j] * W10 + (float)e11[j] * W11);
        acc0 = __builtin_amdgcn_mfma_f32_16x16x32_bf16(a0, fe, acc0, 0, 0, 0);
        acc1 = __builtin_amdgcn_mfma_f32_16x16x32_bf16(a1, fe, acc1, 0, 0, 0);
        acc2 = __builtin_amdgcn_mfma_f32_16x16x32_bf16(a2, fe, acc2, 0, 0, 0);
        acc3 = __builtin_amdgcn_mfma_f32_16x16x32_bf16(a3, fe, acc3, 0, 0, 0);

        b16x8 a4 = wABv[(k * 8 + 4) * 64 + lane];
        b16x8 a5 = wABv[(k * 8 + 5) * 64 + lane];
        b16x8 a6 = wABv[(k * 8 + 6) * 64 + lane];
        b16x8 a7 = wABv[(k * 8 + 7) * 64 + lane];

        if (k < 8) {   // CALC(k+1) + issue its ks0 octets; covered by combine+MFMAs
            CALC_FROM(dyN, dxN, moN, k + 1);
            e00 = P00[0]; e01 = P01[0]; e10 = P10[0]; e11 = P11[0];
        }

        b16x8 fo;
#pragma unroll
        for (int j = 0; j < 8; ++j)
            fo[j] = (__bf16)((float)o00[j] * V00 + (float)o01[j] * V01 +
                             (float)o10[j] * V10 + (float)o11[j] * V11);
        acc0 = __builtin_amdgcn_mfma_f32_16x16x32_bf16(a4, fo, acc0, 0, 0, 0);
        acc1 = __builtin_amdgcn_mfma_f32_16x16x32_bf16(a5, fo, acc1, 0, 0, 0);
        acc2 = __builtin_amdgcn_mfma_f32_16x16x32_bf16(a6, fo, acc2, 0, 0, 0);
        acc3 = __builtin_amdgcn_mfma_f32_16x16x32_bf16(a7, fo, acc3, 0, 0, 0);
    }
#undef CALC_FROM

    // epilogue: C layout row=(q*4+rg) within m-tile, col=n -> pixel rr
    int ob = b * (COUT_ * PLANE) + rblk + g * 16 + n;
    f32x4 bs0 = *(const f32x4*)&bias[q * 4];
    f32x4 bs1 = *(const f32x4*)&bias[16 + q * 4];
    f32x4 bs2 = *(const f32x4*)&bias[32 + q * 4];
    f32x4 bs3 = *(const f32x4*)&bias[48 + q * 4];
#pragma unroll
    for (int rg = 0; rg < 4; ++rg) { int o =      q * 4 + rg; out[ob + o * PLANE] = acc0[rg] + bs0[rg]; }
#pragma unroll
    for (int rg = 0; rg < 4; ++rg) { int o = 16 + q * 4 + rg; out[ob + o * PLANE] = acc1[rg] + bs1[rg]; }
#pragma unroll
    for (int rg = 0; rg < 4; ++rg) { int o = 32 + q * 4 + rg; out[ob + o * PLANE] = acc2[rg] + bs2[rg]; }
#pragma unroll
    for (int rg = 0; rg < 4; ++rg) { int o = 48 + q * 4 + rg; out[ob + o * PLANE] = acc3[rg] + bs3[rg]; }
}

extern "C" void kernel_launch(void* const* d_in, const int* in_sizes, int n_in,
                              void* d_out, int out_size, void* d_ws, size_t ws_size,
                              hipStream_t stream) {
    const float* x      = (const float*)d_in[0];
    const float* w_off  = (const float*)d_in[1];
    const float* b_off  = (const float*)d_in[2];
    const float* weight = (const float*)d_in[3];
    const float* bias   = (const float*)d_in[4];
    float* out = (float*)d_out;

    char* ws = (char*)d_ws;
    __bf16* wAB = (__bf16*)ws;               //  73728 B
    __bf16* wAO = (__bf16*)(ws + 73728);     //  36864 B
    __bf16* xT  = (__bf16*)(ws + 131072);    // 9437184 B (bf16 channel-last)

    prep<<<144, 256, 0, stream>>>(weight, w_off, wAB, wAO);
    xpose<<<NP / 256, 256, 0, stream>>>(x, xT);
    deform_mfma<<<NBLK, 256, 0, stream>>>(xT, wAO, b_off, wAB, bias, out);
}